// Round 4
// baseline (3294.411 us; speedup 1.0000x reference)
//
#include <hip/hip_runtime.h>
#include <math.h>

#define BS 256
#define MM 128
#define NN 1024
#define ITERS 100
#define ALPHA 0.1f

typedef _Float16 half2_t __attribute__((ext_vector_type(2)));

union HU {
  float4 f;
  half2_t h[4];
};

// ---------------------------------------------------------------------------
// AAT: C[b] = A[b] * A[b]^T (128x128). TWO blocks per batch (row-halves) for
// 16 waves/CU. LDS tile k-major [k][m] stride 129. Each block also emits its
// half of the fp16 AT slices (tile is already transposed layout).
#define AST 129
__global__ __launch_bounds__(512) void k_aat(const float* __restrict__ A,
                                             float* __restrict__ C,
                                             _Float16* __restrict__ ATh) {
  __shared__ float As[64 * AST];
  int b = blockIdx.x >> 1;
  int p = blockIdx.x & 1;          // row-half: rows [64p, 64p+64)
  int tid = threadIdx.x;
  const float* Ab = A + (size_t)b * MM * NN;
  float* Cb = C + (size_t)b * MM * MM;
  _Float16* ATb = ATh + (size_t)b * NN * MM;
  int ig = tid >> 4;   // 0..31
  int jg = tid & 15;   // 0..15
  float acc[2][8];
#pragma unroll
  for (int aa = 0; aa < 2; ++aa)
#pragma unroll
    for (int cc = 0; cc < 8; ++cc) acc[aa][cc] = 0.0f;

  for (int t = 0; t < 16; ++t) {
    int k0 = t * 64;
#pragma unroll
    for (int s = 0; s < 4; ++s) {
      int c = tid + s * 512;        // 0..2047
      int m = c >> 4;               // 0..127
      int kk = (c & 15) << 2;       // 0..60
      float4 v = *(const float4*)&Ab[(size_t)m * NN + k0 + kk];
      As[(kk + 0) * AST + m] = v.x;
      As[(kk + 1) * AST + m] = v.y;
      As[(kk + 2) * AST + m] = v.z;
      As[(kk + 3) * AST + m] = v.w;
    }
    __syncthreads();
    // emit this block's half of the fp16 AT k-slice
#pragma unroll
    for (int s = 0; s < 4; ++s) {
      int idx = tid + s * 512;      // 0..2047
      int nl = 32 * p + (idx >> 6); // 32p..32p+31
      int mp = idx & 63;            // m-pair index
      half2_t hv;
      hv.x = (_Float16)As[nl * AST + 2 * mp];
      hv.y = (_Float16)As[nl * AST + 2 * mp + 1];
      *(half2_t*)&ATb[(size_t)(k0 + nl) * MM + 2 * mp] = hv;
    }
#pragma unroll 4
    for (int k = 0; k < 64; ++k) {
      float av[2], bv[8];
      av[0] = As[k * AST + 64 * p + ig];
      av[1] = As[k * AST + 64 * p + 32 + ig];
#pragma unroll
      for (int cc = 0; cc < 8; ++cc) bv[cc] = As[k * AST + jg + 16 * cc];
#pragma unroll
      for (int aa = 0; aa < 2; ++aa)
#pragma unroll
        for (int cc = 0; cc < 8; ++cc) acc[aa][cc] += av[aa] * bv[cc];
    }
    __syncthreads();
  }
#pragma unroll
  for (int aa = 0; aa < 2; ++aa)
#pragma unroll
    for (int cc = 0; cc < 8; ++cc)
      Cb[(size_t)(64 * p + ig + 32 * aa) * MM + jg + 16 * cc] = acc[aa][cc];
}

// ---------------------------------------------------------------------------
// In-place Gauss-Jordan inverse of SPD 128x128. 512 threads; stride-129 LDS
// (col-k reads hit distinct banks instead of 64-way serializing); merged
// pivot-scale into the update -> 2 barriers/step.
#define IST 129
__global__ __launch_bounds__(512) void k_inv(float* __restrict__ G) {
  __shared__ float Msh[MM * IST];
  int b = blockIdx.x;
  int tid = threadIdx.x;
  float* Gb = G + (size_t)b * MM * MM;
#pragma unroll
  for (int s = 0; s < 8; ++s) {
    int idx = (tid + s * 512) * 4;
    float4 v = *(const float4*)&Gb[idx];
    int i = idx >> 7, j = idx & 127;
    Msh[i * IST + j + 0] = v.x;
    Msh[i * IST + j + 1] = v.y;
    Msh[i * IST + j + 2] = v.z;
    Msh[i * IST + j + 3] = v.w;
  }
  __syncthreads();
  int j = tid & 127;
  int i0 = (tid >> 7) * 32;   // this thread owns rows i0..i0+31, column j
  for (int k = 0; k < MM; ++k) {
    float p = 1.0f / Msh[k * IST + k];
    float mkj = Msh[k * IST + j];
    float fik[32];
#pragma unroll
    for (int ii = 0; ii < 32; ++ii) fik[ii] = Msh[(i0 + ii) * IST + k];
    __syncthreads();
    float pmkj = p * mkj;
#pragma unroll
    for (int ii = 0; ii < 32; ++ii) {
      int i = i0 + ii;
      float nij;
      if (i == k)
        nij = (j == k) ? p : pmkj;          // row k scaled; diag = 1/pivot
      else if (j == k)
        nij = -p * fik[ii];                 // col k
      else
        nij = Msh[i * IST + j] - fik[ii] * pmkj;
      Msh[i * IST + j] = nij;
    }
    __syncthreads();
  }
#pragma unroll
  for (int s = 0; s < 8; ++s) {
    int idx = (tid + s * 512) * 4;
    int i = idx >> 7, jj = idx & 127;
    float4 v;
    v.x = Msh[i * IST + jj + 0];
    v.y = Msh[i * IST + jj + 1];
    v.z = Msh[i * IST + jj + 2];
    v.w = Msh[i * IST + jj + 3];
    *(float4*)&Gb[idx] = v;
  }
}

// ---------------------------------------------------------------------------
// Persistent solver: one block per batch, 1024 threads (16 waves).
// A lives ENTIRELY in registers: each thread's 16 column-fragments (16 x
// float4 of fp16 = 64 VGPRs) are iteration-invariant -> loaded once in the
// prologue, zero A traffic in the loop. LDS only holds the small exchange
// vectors (s, u, t-partials) and thresholds.
#define TRP 132
__global__ __launch_bounds__(1024) void k_main(
    const _Float16* __restrict__ AT, const float* __restrict__ G,
    const float* __restrict__ bvec, const float* __restrict__ D1,
    const float* __restrict__ D2, float* __restrict__ out) {
  __shared__ float td_sh[NN];
  __shared__ float di_sh[NN];
  __shared__ float b_sh[MM];
  __shared__ float s_sh[MM];
  __shared__ __align__(16) _Float16 u_h[MM];
  __shared__ __align__(16) float t_redW[16][TRP];

  int b = blockIdx.x;
  int tid = threadIdx.x;
  const _Float16* ATb = AT + (size_t)b * NN * MM;
  const float* Gb = G + (size_t)b * MM * MM;

  // ---- G fragment: 8 threads per row, 16 elems each (16 VGPRs)
  int sub = tid & 7, r = tid >> 3;
  float g[16];
#pragma unroll
  for (int s = 0; s < 4; ++s) {
    float4 v = *(const float4*)&Gb[(size_t)r * MM + 16 * sub + 4 * s];
    g[4 * s + 0] = v.x; g[4 * s + 1] = v.y;
    g[4 * s + 2] = v.z; g[4 * s + 3] = v.w;
  }
  {
    float d1 = D1[(size_t)b * NN + tid];
    float d2 = D2[(size_t)b * NN + tid];
    td_sh[tid] = ALPHA * fabsf(d1);
    di_sh[tid] = 1.0f / (1.0f + 2.0f * ALPHA * d2 * d2);
  }
  if (tid < MM) {
    float bb = bvec[(size_t)b * MM + tid];
    b_sh[tid] = bb;
    s_sh[tid] = -bb;   // s_0 = A*y_0 - b = -b
  }

  int l16 = tid & 15;          // lane in 16-group
  int grp4 = (tid >> 4) & 3;   // group within wave
  int w = tid >> 6;            // wave 0..15
  int mbase = 8 * l16;

  // ---- A fragments into registers (iteration-invariant, 64 VGPRs)
  HU af[16];
#pragma unroll
  for (int s = 0; s < 16; ++s)
    af[s].f = *(const float4*)&ATb[(size_t)(64 * w + 4 * s + grp4) * MM + mbase];

  float zreg[16];
#pragma unroll
  for (int s = 0; s < 16; ++s) zreg[s] = 0.0f;
  __syncthreads();

  for (int it = 0; it < ITERS; ++it) {
    bool last = (it == ITERS - 1);
    // ---- u = G * s  (8 threads per row)
    {
      float up = 0.0f;
      int j0 = 16 * sub;
#pragma unroll
      for (int jj = 0; jj < 16; ++jj) up += g[jj] * s_sh[j0 + jj];
      up += __shfl_xor(up, 1);
      up += __shfl_xor(up, 2);
      up += __shfl_xor(up, 4);
      if (sub == 0) u_h[r] = (_Float16)up;
    }
    __syncthreads();
    HU uu;
    uu.f = *(const float4*)&u_h[mbase];
    float t[8];
#pragma unroll
    for (int k = 0; k < 8; ++k) t[k] = 0.0f;

#pragma unroll
    for (int s = 0; s < 16; ++s) {
      int n = 64 * w + 4 * s + grp4;
      float cp = 0.0f;
      cp = __builtin_amdgcn_fdot2(af[s].h[0], uu.h[0], cp, false);
      cp = __builtin_amdgcn_fdot2(af[s].h[1], uu.h[1], cp, false);
      cp = __builtin_amdgcn_fdot2(af[s].h[2], uu.h[2], cp, false);
      cp = __builtin_amdgcn_fdot2(af[s].h[3], uu.h[3], cp, false);
      cp += __shfl_xor(cp, 1);
      cp += __shfl_xor(cp, 2);
      cp += __shfl_xor(cp, 4);
      cp += __shfl_xor(cp, 8);   // all 16 lanes hold corr[n]
      float zn = zreg[s];
      float td = td_sh[n];
      float di = di_sh[n];
      float xm = zn - td, xp = zn + td;
      float xh = xm > 0.0f ? xm * di : (xp < 0.0f ? xp * di : 0.0f);
      if (!last) {
        float z1 = xh - cp;                     // z_{i+1}
        float xm1 = z1 - td, xp1 = z1 + td;
        float xh1 = xm1 > 0.0f ? xm1 * di : (xp1 < 0.0f ? xp1 * di : 0.0f);
        float y = 2.0f * xh1 - z1;              // y_{i+1}
        zreg[s] = z1;
        t[0] += (float)af[s].h[0].x * y; t[1] += (float)af[s].h[0].y * y;
        t[2] += (float)af[s].h[1].x * y; t[3] += (float)af[s].h[1].y * y;
        t[4] += (float)af[s].h[2].x * y; t[5] += (float)af[s].h[2].y * y;
        t[6] += (float)af[s].h[3].x * y; t[7] += (float)af[s].h[3].y * y;
      } else {
        float y = 2.0f * xh - zn;               // y_99 from z_99
        zreg[s] = y - cp;                       // x_99 (output)
      }
    }

    if (!last) {
      // ---- in-wave cross-group reduce, then 16-wave LDS reduce
#pragma unroll
      for (int k = 0; k < 8; ++k) {
        t[k] += __shfl_xor(t[k], 16);
        t[k] += __shfl_xor(t[k], 32);
      }
      if (grp4 == 0) {
        float4 ta; ta.x = t[0]; ta.y = t[1]; ta.z = t[2]; ta.w = t[3];
        float4 tb; tb.x = t[4]; tb.y = t[5]; tb.z = t[6]; tb.w = t[7];
        *(float4*)&t_redW[w][mbase] = ta;
        *(float4*)&t_redW[w][mbase + 4] = tb;
      }
      __syncthreads();
      if (tid < MM) {
        float ssum = -b_sh[tid];
#pragma unroll
        for (int h = 0; h < 16; ++h) ssum += t_redW[h][tid];
        s_sh[tid] = ssum;        // s = A*y - b for next pass's u
      }
      __syncthreads();
    }
  }

  if (l16 == 0) {
    float* outb = out + (size_t)b * NN;
#pragma unroll
    for (int s = 0; s < 16; ++s) outb[64 * w + 4 * s + grp4] = zreg[s];
  }
}

// ---------------------------------------------------------------------------
extern "C" void kernel_launch(void* const* d_in, const int* in_sizes, int n_in,
                              void* d_out, int out_size, void* d_ws, size_t ws_size,
                              hipStream_t stream) {
  const float* A  = (const float*)d_in[0];  // (BS, M, N)
  const float* bv = (const float*)d_in[1];  // (BS, M)
  const float* D1 = (const float*)d_in[2];  // (BS, N)
  const float* D2 = (const float*)d_in[3];  // (BS, N)
  float* out = (float*)d_out;               // (BS, N)

  _Float16* ATh = (_Float16*)d_ws;                              // 67 MB
  float* G = (float*)((char*)d_ws + (size_t)BS * NN * MM * 2);  // 16.7 MB

  k_aat<<<BS * 2, 512, 0, stream>>>(A, G, ATh);
  k_inv<<<BS, 512, 0, stream>>>(G);
  k_main<<<BS, 1024, 0, stream>>>(ATh, G, bv, D1, D2, out);
}

// Round 5
// 2388.167 us; speedup vs baseline: 1.3795x; 1.3795x over previous
//
#include <hip/hip_runtime.h>
#include <math.h>

#define BS 256
#define MM 128
#define NN 1024
#define ITERS 100
#define ALPHA 0.1f

typedef _Float16 half8 __attribute__((ext_vector_type(8)));
typedef _Float16 half2v __attribute__((ext_vector_type(2)));

// ---------------------------------------------------------------------------
// AAT: C[b] = A[b] * A[b]^T (128x128). TWO blocks per batch (row-halves).
// LDS tile k-major [k][m] stride 129. Each block also emits its half of the
// fp16 AT slices (tile is already transposed layout).
#define AST 129
__global__ __launch_bounds__(512) void k_aat(const float* __restrict__ A,
                                             float* __restrict__ C,
                                             _Float16* __restrict__ ATh) {
  __shared__ float As[64 * AST];
  int b = blockIdx.x >> 1;
  int p = blockIdx.x & 1;          // row-half: rows [64p, 64p+64)
  int tid = threadIdx.x;
  const float* Ab = A + (size_t)b * MM * NN;
  float* Cb = C + (size_t)b * MM * MM;
  _Float16* ATb = ATh + (size_t)b * NN * MM;
  int ig = tid >> 4;   // 0..31
  int jg = tid & 15;   // 0..15
  float acc[2][8];
#pragma unroll
  for (int aa = 0; aa < 2; ++aa)
#pragma unroll
    for (int cc = 0; cc < 8; ++cc) acc[aa][cc] = 0.0f;

  for (int t = 0; t < 16; ++t) {
    int k0 = t * 64;
#pragma unroll
    for (int s = 0; s < 4; ++s) {
      int c = tid + s * 512;        // 0..2047
      int m = c >> 4;               // 0..127
      int kk = (c & 15) << 2;       // 0..60
      float4 v = *(const float4*)&Ab[(size_t)m * NN + k0 + kk];
      As[(kk + 0) * AST + m] = v.x;
      As[(kk + 1) * AST + m] = v.y;
      As[(kk + 2) * AST + m] = v.z;
      As[(kk + 3) * AST + m] = v.w;
    }
    __syncthreads();
    // emit this block's half of the fp16 AT k-slice
#pragma unroll
    for (int s = 0; s < 4; ++s) {
      int idx = tid + s * 512;      // 0..2047
      int nl = 32 * p + (idx >> 6); // 32p..32p+31
      int mp = idx & 63;            // m-pair index
      half2v hv;
      hv[0] = (_Float16)As[nl * AST + 2 * mp];
      hv[1] = (_Float16)As[nl * AST + 2 * mp + 1];
      *(half2v*)&ATb[(size_t)(k0 + nl) * MM + 2 * mp] = hv;
    }
#pragma unroll 4
    for (int k = 0; k < 64; ++k) {
      float av[2], bv[8];
      av[0] = As[k * AST + 64 * p + ig];
      av[1] = As[k * AST + 64 * p + 32 + ig];
#pragma unroll
      for (int cc = 0; cc < 8; ++cc) bv[cc] = As[k * AST + jg + 16 * cc];
#pragma unroll
      for (int aa = 0; aa < 2; ++aa)
#pragma unroll
        for (int cc = 0; cc < 8; ++cc) acc[aa][cc] += av[aa] * bv[cc];
    }
    __syncthreads();
  }
#pragma unroll
  for (int aa = 0; aa < 2; ++aa)
#pragma unroll
    for (int cc = 0; cc < 8; ++cc)
      Cb[(size_t)(64 * p + ig + 32 * aa) * MM + jg + 16 * cc] = acc[aa][cc];
}

// ---------------------------------------------------------------------------
// In-place Gauss-Jordan inverse of SPD 128x128. 512 threads; stride-129 LDS;
// merged pivot-scale into the update -> 2 barriers/step.
#define IST 129
__global__ __launch_bounds__(512) void k_inv(float* __restrict__ G) {
  __shared__ float Msh[MM * IST];
  int b = blockIdx.x;
  int tid = threadIdx.x;
  float* Gb = G + (size_t)b * MM * MM;
#pragma unroll
  for (int s = 0; s < 8; ++s) {
    int idx = (tid + s * 512) * 4;
    float4 v = *(const float4*)&Gb[idx];
    int i = idx >> 7, j = idx & 127;
    Msh[i * IST + j + 0] = v.x;
    Msh[i * IST + j + 1] = v.y;
    Msh[i * IST + j + 2] = v.z;
    Msh[i * IST + j + 3] = v.w;
  }
  __syncthreads();
  int j = tid & 127;
  int i0 = (tid >> 7) * 32;   // this thread owns rows i0..i0+31, column j
  for (int k = 0; k < MM; ++k) {
    float p = 1.0f / Msh[k * IST + k];
    float mkj = Msh[k * IST + j];
    float fik[32];
#pragma unroll
    for (int ii = 0; ii < 32; ++ii) fik[ii] = Msh[(i0 + ii) * IST + k];
    __syncthreads();
    float pmkj = p * mkj;
#pragma unroll
    for (int ii = 0; ii < 32; ++ii) {
      int i = i0 + ii;
      float nij;
      if (i == k)
        nij = (j == k) ? p : pmkj;          // row k scaled; diag = 1/pivot
      else if (j == k)
        nij = -p * fik[ii];                 // col k
      else
        nij = Msh[i * IST + j] - fik[ii] * pmkj;
      Msh[i * IST + j] = nij;
    }
    __syncthreads();
  }
#pragma unroll
  for (int s = 0; s < 8; ++s) {
    int idx = (tid + s * 512) * 4;
    int i = idx >> 7, jj = idx & 127;
    float4 v;
    v.x = Msh[i * IST + jj + 0];
    v.y = Msh[i * IST + jj + 1];
    v.z = Msh[i * IST + jj + 2];
    v.w = Msh[i * IST + jj + 3];
    *(float4*)&Gb[idx] = v;
  }
}

// ---------------------------------------------------------------------------
// Persistent solver: one block per batch, 1024 threads (16 waves).
// A split: each 16-lane group owns 16 columns; 8 live in REGISTERS (half8
// af[8], 32 VGPRs, no unions -> SROA-safe), 8 live in LDS (131 KB). Zero
// global A traffic inside the iteration loop.
#define TRP 132
__global__ __launch_bounds__(1024, 4) void k_main(
    const _Float16* __restrict__ AT, const float* __restrict__ G,
    const float* __restrict__ bvec, const float* __restrict__ D1,
    const float* __restrict__ D2, float* __restrict__ out) {
  __shared__ __align__(16) _Float16 AL[512 * MM];   // 131 KB
  __shared__ float td_sh[NN];
  __shared__ float di_sh[NN];
  __shared__ float b_sh[MM];
  __shared__ float s_sh[MM];
  __shared__ __align__(16) _Float16 u_h[MM];
  __shared__ __align__(16) float t_redW[16][TRP];

  int b = blockIdx.x;
  int tid = threadIdx.x;
  const _Float16* ATb = AT + (size_t)b * NN * MM;
  const float* Gb = G + (size_t)b * MM * MM;

  // ---- G fragment: 8 threads per row, 16 elems each (16 VGPRs)
  int sub = tid & 7, r = tid >> 3;
  float g[16];
#pragma unroll
  for (int s = 0; s < 4; ++s) {
    float4 v = *(const float4*)&Gb[(size_t)r * MM + 16 * sub + 4 * s];
    g[4 * s + 0] = v.x; g[4 * s + 1] = v.y;
    g[4 * s + 2] = v.z; g[4 * s + 3] = v.w;
  }
  {
    float d1 = D1[(size_t)b * NN + tid];
    float d2 = D2[(size_t)b * NN + tid];
    td_sh[tid] = ALPHA * fabsf(d1);
    di_sh[tid] = 1.0f / (1.0f + 2.0f * ALPHA * d2 * d2);
  }
  if (tid < MM) {
    float bb = bvec[(size_t)b * MM + tid];
    b_sh[tid] = bb;
    s_sh[tid] = -bb;   // s_0 = A*y_0 - b = -b
  }

  int l16 = tid & 15;          // lane in 16-group
  int grp4 = (tid >> 4) & 3;   // group within wave
  int w = tid >> 6;            // wave 0..15
  int mbase = 8 * l16;

  // ---- LDS half of A: AL col cL = 32*w + 4*(s-8) + g4  <->  n = 32*w+32+cL
#pragma unroll
  for (int i = 0; i < 8; ++i) {
    int c = tid + 1024 * i;          // 16B chunk id, 0..8191
    int col = c >> 4;                // 0..511 (16 chunks per col)
    int m8 = (c & 15) * 8;           // half-index within col
    int n = 32 * (col >> 5) + 32 + col;
    *(half8*)&AL[col * MM + m8] = *(const half8*)&ATb[(size_t)n * MM + m8];
  }

  // ---- register half of A: columns 64*w + 4*s + g4, s = 0..7 (32 VGPRs)
  half8 af[8];
#pragma unroll
  for (int s = 0; s < 8; ++s)
    af[s] = *(const half8*)&ATb[(size_t)(64 * w + 4 * s + grp4) * MM + mbase];

  float zreg[16];
#pragma unroll
  for (int s = 0; s < 16; ++s) zreg[s] = 0.0f;
  __syncthreads();

  for (int it = 0; it < ITERS; ++it) {
    bool last = (it == ITERS - 1);
    // ---- u = G * s  (8 threads per row)
    {
      float up = 0.0f;
      int j0 = 16 * sub;
#pragma unroll
      for (int jj = 0; jj < 16; ++jj) up += g[jj] * s_sh[j0 + jj];
      up += __shfl_xor(up, 1);
      up += __shfl_xor(up, 2);
      up += __shfl_xor(up, 4);
      if (sub == 0) u_h[r] = (_Float16)up;
    }
    __syncthreads();
    half8 uu = *(const half8*)&u_h[mbase];
    half2v u0 = __builtin_shufflevector(uu, uu, 0, 1);
    half2v u1 = __builtin_shufflevector(uu, uu, 2, 3);
    half2v u2 = __builtin_shufflevector(uu, uu, 4, 5);
    half2v u3 = __builtin_shufflevector(uu, uu, 6, 7);
    float t[8];
#pragma unroll
    for (int k = 0; k < 8; ++k) t[k] = 0.0f;

#pragma unroll
    for (int s = 0; s < 16; ++s) {
      int n = 64 * w + 4 * s + grp4;
      half8 av;
      if (s < 8)
        av = af[s];
      else
        av = *(const half8*)&AL[(32 * w + 4 * (s - 8) + grp4) * MM + mbase];
      half2v a0 = __builtin_shufflevector(av, av, 0, 1);
      half2v a1 = __builtin_shufflevector(av, av, 2, 3);
      half2v a2 = __builtin_shufflevector(av, av, 4, 5);
      half2v a3 = __builtin_shufflevector(av, av, 6, 7);
      float cp = 0.0f;
      cp = __builtin_amdgcn_fdot2(a0, u0, cp, false);
      cp = __builtin_amdgcn_fdot2(a1, u1, cp, false);
      cp = __builtin_amdgcn_fdot2(a2, u2, cp, false);
      cp = __builtin_amdgcn_fdot2(a3, u3, cp, false);
      cp += __shfl_xor(cp, 1);
      cp += __shfl_xor(cp, 2);
      cp += __shfl_xor(cp, 4);
      cp += __shfl_xor(cp, 8);   // all 16 lanes hold corr[n]
      float zn = zreg[s];
      float td = td_sh[n];
      float di = di_sh[n];
      float xm = zn - td, xp = zn + td;
      float xh = xm > 0.0f ? xm * di : (xp < 0.0f ? xp * di : 0.0f);
      if (!last) {
        float z1 = xh - cp;                     // z_{i+1}
        float xm1 = z1 - td, xp1 = z1 + td;
        float xh1 = xm1 > 0.0f ? xm1 * di : (xp1 < 0.0f ? xp1 * di : 0.0f);
        float y = 2.0f * xh1 - z1;              // y_{i+1}
        zreg[s] = z1;
#pragma unroll
        for (int k = 0; k < 8; ++k) t[k] += (float)av[k] * y;
      } else {
        float y = 2.0f * xh - zn;               // y_99 from z_99
        zreg[s] = y - cp;                       // x_99 (output)
      }
    }

    if (!last) {
      // ---- in-wave cross-group reduce, then 16-wave LDS reduce
#pragma unroll
      for (int k = 0; k < 8; ++k) {
        t[k] += __shfl_xor(t[k], 16);
        t[k] += __shfl_xor(t[k], 32);
      }
      if (grp4 == 0) {
        float4 ta; ta.x = t[0]; ta.y = t[1]; ta.z = t[2]; ta.w = t[3];
        float4 tb; tb.x = t[4]; tb.y = t[5]; tb.z = t[6]; tb.w = t[7];
        *(float4*)&t_redW[w][mbase] = ta;
        *(float4*)&t_redW[w][mbase + 4] = tb;
      }
      __syncthreads();
      if (tid < MM) {
        float ssum = -b_sh[tid];
#pragma unroll
        for (int h = 0; h < 16; ++h) ssum += t_redW[h][tid];
        s_sh[tid] = ssum;        // s = A*y - b for next pass's u
      }
      __syncthreads();
    }
  }

  if (l16 == 0) {
    float* outb = out + (size_t)b * NN;
#pragma unroll
    for (int s = 0; s < 16; ++s) outb[64 * w + 4 * s + grp4] = zreg[s];
  }
}

// ---------------------------------------------------------------------------
extern "C" void kernel_launch(void* const* d_in, const int* in_sizes, int n_in,
                              void* d_out, int out_size, void* d_ws, size_t ws_size,
                              hipStream_t stream) {
  const float* A  = (const float*)d_in[0];  // (BS, M, N)
  const float* bv = (const float*)d_in[1];  // (BS, M)
  const float* D1 = (const float*)d_in[2];  // (BS, N)
  const float* D2 = (const float*)d_in[3];  // (BS, N)
  float* out = (float*)d_out;               // (BS, N)

  _Float16* ATh = (_Float16*)d_ws;                              // 67 MB
  float* G = (float*)((char*)d_ws + (size_t)BS * NN * MM * 2);  // 16.7 MB

  k_aat<<<BS * 2, 512, 0, stream>>>(A, G, ATh);
  k_inv<<<BS, 512, 0, stream>>>(G);
  k_main<<<BS, 1024, 0, stream>>>(ATh, G, bv, D1, D2, out);
}

// Round 7
// 2384.262 us; speedup vs baseline: 1.3817x; 1.0016x over previous
//
#include <hip/hip_runtime.h>
#include <math.h>

#define BS 256
#define MM 128
#define NN 1024
#define ITERS 100
#define ALPHA 0.1f

typedef _Float16 half8 __attribute__((ext_vector_type(8)));
typedef _Float16 half2v __attribute__((ext_vector_type(2)));

// ---------------------------------------------------------------------------
// AAT: C[b] = A[b] * A[b]^T (128x128). TWO blocks per batch (row-halves).
// LDS tile k-major [k][m] stride 129. Each block also emits its half of the
// fp16 AT slices (tile is already transposed layout).
#define AST 129
__global__ __launch_bounds__(512) void k_aat(const float* __restrict__ A,
                                             float* __restrict__ C,
                                             _Float16* __restrict__ ATh) {
  __shared__ float As[64 * AST];
  int b = blockIdx.x >> 1;
  int p = blockIdx.x & 1;          // row-half: rows [64p, 64p+64)
  int tid = threadIdx.x;
  const float* Ab = A + (size_t)b * MM * NN;
  float* Cb = C + (size_t)b * MM * MM;
  _Float16* ATb = ATh + (size_t)b * NN * MM;
  int ig = tid >> 4;   // 0..31
  int jg = tid & 15;   // 0..15
  float acc[2][8];
#pragma unroll
  for (int aa = 0; aa < 2; ++aa)
#pragma unroll
    for (int cc = 0; cc < 8; ++cc) acc[aa][cc] = 0.0f;

  for (int t = 0; t < 16; ++t) {
    int k0 = t * 64;
#pragma unroll
    for (int s = 0; s < 4; ++s) {
      int c = tid + s * 512;        // 0..2047
      int m = c >> 4;               // 0..127
      int kk = (c & 15) << 2;       // 0..60
      float4 v = *(const float4*)&Ab[(size_t)m * NN + k0 + kk];
      As[(kk + 0) * AST + m] = v.x;
      As[(kk + 1) * AST + m] = v.y;
      As[(kk + 2) * AST + m] = v.z;
      As[(kk + 3) * AST + m] = v.w;
    }
    __syncthreads();
    // emit this block's half of the fp16 AT k-slice
#pragma unroll
    for (int s = 0; s < 4; ++s) {
      int idx = tid + s * 512;      // 0..2047
      int nl = 32 * p + (idx >> 6); // 32p..32p+31
      int mp = idx & 63;            // m-pair index
      half2v hv;
      hv[0] = (_Float16)As[nl * AST + 2 * mp];
      hv[1] = (_Float16)As[nl * AST + 2 * mp + 1];
      *(half2v*)&ATb[(size_t)(k0 + nl) * MM + 2 * mp] = hv;
    }
#pragma unroll 4
    for (int k = 0; k < 64; ++k) {
      float av[2], bv[8];
      av[0] = As[k * AST + 64 * p + ig];
      av[1] = As[k * AST + 64 * p + 32 + ig];
#pragma unroll
      for (int cc = 0; cc < 8; ++cc) bv[cc] = As[k * AST + jg + 16 * cc];
#pragma unroll
      for (int aa = 0; aa < 2; ++aa)
#pragma unroll
        for (int cc = 0; cc < 8; ++cc) acc[aa][cc] += av[aa] * bv[cc];
    }
    __syncthreads();
  }
#pragma unroll
  for (int aa = 0; aa < 2; ++aa)
#pragma unroll
    for (int cc = 0; cc < 8; ++cc)
      Cb[(size_t)(64 * p + ig + 32 * aa) * MM + jg + 16 * cc] = acc[aa][cc];
}

// ---------------------------------------------------------------------------
// In-place Gauss-Jordan inverse of SPD 128x128. 512 threads; stride-129 LDS;
// merged pivot-scale into the update -> 2 barriers/step.
#define IST 129
__global__ __launch_bounds__(512) void k_inv(float* __restrict__ G) {
  __shared__ float Msh[MM * IST];
  int b = blockIdx.x;
  int tid = threadIdx.x;
  float* Gb = G + (size_t)b * MM * MM;
#pragma unroll
  for (int s = 0; s < 8; ++s) {
    int idx = (tid + s * 512) * 4;
    float4 v = *(const float4*)&Gb[idx];
    int i = idx >> 7, j = idx & 127;
    Msh[i * IST + j + 0] = v.x;
    Msh[i * IST + j + 1] = v.y;
    Msh[i * IST + j + 2] = v.z;
    Msh[i * IST + j + 3] = v.w;
  }
  __syncthreads();
  int j = tid & 127;
  int i0 = (tid >> 7) * 32;   // this thread owns rows i0..i0+31, column j
  for (int k = 0; k < MM; ++k) {
    float p = 1.0f / Msh[k * IST + k];
    float mkj = Msh[k * IST + j];
    float fik[32];
#pragma unroll
    for (int ii = 0; ii < 32; ++ii) fik[ii] = Msh[(i0 + ii) * IST + k];
    __syncthreads();
    float pmkj = p * mkj;
#pragma unroll
    for (int ii = 0; ii < 32; ++ii) {
      int i = i0 + ii;
      float nij;
      if (i == k)
        nij = (j == k) ? p : pmkj;          // row k scaled; diag = 1/pivot
      else if (j == k)
        nij = -p * fik[ii];                 // col k
      else
        nij = Msh[i * IST + j] - fik[ii] * pmkj;
      Msh[i * IST + j] = nij;
    }
    __syncthreads();
  }
#pragma unroll
  for (int s = 0; s < 8; ++s) {
    int idx = (tid + s * 512) * 4;
    int i = idx >> 7, jj = idx & 127;
    float4 v;
    v.x = Msh[i * IST + jj + 0];
    v.y = Msh[i * IST + jj + 1];
    v.z = Msh[i * IST + jj + 2];
    v.w = Msh[i * IST + jj + 3];
    *(float4*)&Gb[idx] = v;
  }
}

// ---------------------------------------------------------------------------
// Persistent solver: one block per batch, 1024 threads (16 waves, exactly
// 4 waves/EU -> 128-VGPR budget via amdgpu_waves_per_eu(4,4)).
// A split: 8 cols/group in REGISTERS, each fragment held as 4 pinned scalar
// floats (opaque asm -> compiler cannot rematerialize the loads inside the
// loop, which caused rounds 4/5's 100x re-fetch). 8 cols/group in LDS.
#define TRP 132
__global__ __attribute__((amdgpu_waves_per_eu(4, 4)))
__launch_bounds__(1024) void k_main(
    const _Float16* __restrict__ AT, const float* __restrict__ G,
    const float* __restrict__ bvec, const float* __restrict__ D1,
    const float* __restrict__ D2, float* __restrict__ out) {
  __shared__ __align__(16) _Float16 AL[512 * MM];   // 131 KB
  __shared__ float td_sh[NN];
  __shared__ float di_sh[NN];
  __shared__ float b_sh[MM];
  __shared__ float s_sh[MM];
  __shared__ __align__(16) _Float16 u_h[MM];
  __shared__ __align__(16) float t_redW[16][TRP];

  int b = blockIdx.x;
  int tid = threadIdx.x;
  const _Float16* ATb = AT + (size_t)b * NN * MM;
  const float* Gb = G + (size_t)b * MM * MM;

  // ---- G fragment: 8 threads per row, 16 elems each (16 VGPRs)
  int sub = tid & 7, r = tid >> 3;
  float g[16];
#pragma unroll
  for (int s = 0; s < 4; ++s) {
    float4 v = *(const float4*)&Gb[(size_t)r * MM + 16 * sub + 4 * s];
    g[4 * s + 0] = v.x; g[4 * s + 1] = v.y;
    g[4 * s + 2] = v.z; g[4 * s + 3] = v.w;
  }
  {
    float d1 = D1[(size_t)b * NN + tid];
    float d2 = D2[(size_t)b * NN + tid];
    td_sh[tid] = ALPHA * fabsf(d1);
    di_sh[tid] = 1.0f / (1.0f + 2.0f * ALPHA * d2 * d2);
  }
  if (tid < MM) {
    float bb = bvec[(size_t)b * MM + tid];
    b_sh[tid] = bb;
    s_sh[tid] = -bb;   // s_0 = A*y_0 - b = -b
  }

  int l16 = tid & 15;          // lane in 16-group
  int grp4 = (tid >> 4) & 3;   // group within wave
  int w = tid >> 6;            // wave 0..15
  int mbase = 8 * l16;

  // ---- LDS half of A: AL col cL = 32*w + cL  <->  n = 64*w + 32 + cL
#pragma unroll
  for (int i = 0; i < 8; ++i) {
    int c = tid + 1024 * i;          // 16B chunk id, 0..8191
    int col = c >> 4;                // 0..511 (16 chunks per col)
    int m8 = (c & 15) * 8;           // half-index within col
    int n = 32 * (col >> 5) + 32 + col;
    *(half8*)&AL[col * MM + m8] = *(const half8*)&ATb[(size_t)n * MM + m8];
  }

  // ---- register half of A: columns 64*w + 4*s + grp4, s = 0..7.
  // 32 scalar floats (= 32 VGPRs), each pinned via opaque scalar asm.
  float af0[8], af1[8], af2[8], af3[8];
#pragma unroll
  for (int s = 0; s < 8; ++s) {
    float4 v = *(const float4*)&ATb[(size_t)(64 * w + 4 * s + grp4) * MM + mbase];
    af0[s] = v.x; af1[s] = v.y; af2[s] = v.z; af3[s] = v.w;
  }
#pragma unroll
  for (int s = 0; s < 8; ++s) {
    asm volatile("" : "+v"(af0[s]));
    asm volatile("" : "+v"(af1[s]));
    asm volatile("" : "+v"(af2[s]));
    asm volatile("" : "+v"(af3[s]));
  }

  float zreg[16];
#pragma unroll
  for (int s = 0; s < 16; ++s) zreg[s] = 0.0f;
  __syncthreads();

  for (int it = 0; it < ITERS; ++it) {
    bool last = (it == ITERS - 1);
    // ---- u = G * s  (8 threads per row)
    {
      float up = 0.0f;
      int j0 = 16 * sub;
#pragma unroll
      for (int jj = 0; jj < 16; ++jj) up += g[jj] * s_sh[j0 + jj];
      up += __shfl_xor(up, 1);
      up += __shfl_xor(up, 2);
      up += __shfl_xor(up, 4);
      if (sub == 0) u_h[r] = (_Float16)up;
    }
    __syncthreads();
    half8 uu = *(const half8*)&u_h[mbase];
    half2v u0 = __builtin_shufflevector(uu, uu, 0, 1);
    half2v u1 = __builtin_shufflevector(uu, uu, 2, 3);
    half2v u2 = __builtin_shufflevector(uu, uu, 4, 5);
    half2v u3 = __builtin_shufflevector(uu, uu, 6, 7);
    float t[8];
#pragma unroll
    for (int k = 0; k < 8; ++k) t[k] = 0.0f;

#pragma unroll
    for (int s = 0; s < 16; ++s) {
      int n = 64 * w + 4 * s + grp4;
      half2v a0, a1, a2, a3;
      if (s < 8) {
        a0 = __builtin_bit_cast(half2v, af0[s]);
        a1 = __builtin_bit_cast(half2v, af1[s]);
        a2 = __builtin_bit_cast(half2v, af2[s]);
        a3 = __builtin_bit_cast(half2v, af3[s]);
      } else {
        half8 av = *(const half8*)&AL[(32 * w + 4 * (s - 8) + grp4) * MM + mbase];
        a0 = __builtin_shufflevector(av, av, 0, 1);
        a1 = __builtin_shufflevector(av, av, 2, 3);
        a2 = __builtin_shufflevector(av, av, 4, 5);
        a3 = __builtin_shufflevector(av, av, 6, 7);
      }
      float cp = 0.0f;
      cp = __builtin_amdgcn_fdot2(a0, u0, cp, false);
      cp = __builtin_amdgcn_fdot2(a1, u1, cp, false);
      cp = __builtin_amdgcn_fdot2(a2, u2, cp, false);
      cp = __builtin_amdgcn_fdot2(a3, u3, cp, false);
      cp += __shfl_xor(cp, 1);
      cp += __shfl_xor(cp, 2);
      cp += __shfl_xor(cp, 4);
      cp += __shfl_xor(cp, 8);   // all 16 lanes hold corr[n]
      float zn = zreg[s];
      float td = td_sh[n];
      float di = di_sh[n];
      float xm = zn - td, xp = zn + td;
      float xh = xm > 0.0f ? xm * di : (xp < 0.0f ? xp * di : 0.0f);
      if (!last) {
        float z1 = xh - cp;                     // z_{i+1}
        float xm1 = z1 - td, xp1 = z1 + td;
        float xh1 = xm1 > 0.0f ? xm1 * di : (xp1 < 0.0f ? xp1 * di : 0.0f);
        float y = 2.0f * xh1 - z1;              // y_{i+1}
        zreg[s] = z1;
        t[0] += (float)a0[0] * y; t[1] += (float)a0[1] * y;
        t[2] += (float)a1[0] * y; t[3] += (float)a1[1] * y;
        t[4] += (float)a2[0] * y; t[5] += (float)a2[1] * y;
        t[6] += (float)a3[0] * y; t[7] += (float)a3[1] * y;
      } else {
        float y = 2.0f * xh - zn;               // y_99 from z_99
        zreg[s] = y - cp;                       // x_99 (output)
      }
    }

    if (!last) {
      // ---- in-wave cross-group reduce, then 16-wave LDS reduce
#pragma unroll
      for (int k = 0; k < 8; ++k) {
        t[k] += __shfl_xor(t[k], 16);
        t[k] += __shfl_xor(t[k], 32);
      }
      if (grp4 == 0) {
        float4 ta; ta.x = t[0]; ta.y = t[1]; ta.z = t[2]; ta.w = t[3];
        float4 tb; tb.x = t[4]; tb.y = t[5]; tb.z = t[6]; tb.w = t[7];
        *(float4*)&t_redW[w][mbase] = ta;
        *(float4*)&t_redW[w][mbase + 4] = tb;
      }
      __syncthreads();
      if (tid < MM) {
        float ssum = -b_sh[tid];
#pragma unroll
        for (int h = 0; h < 16; ++h) ssum += t_redW[h][tid];
        s_sh[tid] = ssum;        // s = A*y - b for next pass's u
      }
      __syncthreads();
    }
  }

  if (l16 == 0) {
    float* outb = out + (size_t)b * NN;
#pragma unroll
    for (int s = 0; s < 16; ++s) outb[64 * w + 4 * s + grp4] = zreg[s];
  }
}

// ---------------------------------------------------------------------------
extern "C" void kernel_launch(void* const* d_in, const int* in_sizes, int n_in,
                              void* d_out, int out_size, void* d_ws, size_t ws_size,
                              hipStream_t stream) {
  const float* A  = (const float*)d_in[0];  // (BS, M, N)
  const float* bv = (const float*)d_in[1];  // (BS, M)
  const float* D1 = (const float*)d_in[2];  // (BS, N)
  const float* D2 = (const float*)d_in[3];  // (BS, N)
  float* out = (float*)d_out;               // (BS, N)

  _Float16* ATh = (_Float16*)d_ws;                              // 67 MB
  float* G = (float*)((char*)d_ws + (size_t)BS * NN * MM * 2);  // 16.7 MB

  k_aat<<<BS * 2, 512, 0, stream>>>(A, G, ATh);
  k_inv<<<BS, 512, 0, stream>>>(G);
  k_main<<<BS, 1024, 0, stream>>>(ATh, G, bv, D1, D2, out);
}

// Round 8
// 1491.415 us; speedup vs baseline: 2.2089x; 1.5987x over previous
//
#include <hip/hip_runtime.h>
#include <math.h>

#define BS 256
#define MM 128
#define NN 1024
#define ITERS 100
#define ALPHA 0.1f

typedef _Float16 half8 __attribute__((ext_vector_type(8)));
typedef _Float16 half2v __attribute__((ext_vector_type(2)));

// ---------------------------------------------------------------------------
// AAT: C[b] = A[b] * A[b]^T (128x128). TWO blocks per batch (row-halves).
// LDS tile k-major [k][m] stride 129. Each block also emits its half of the
// fp16 AT slices (tile is already transposed layout).
#define AST 129
__global__ __launch_bounds__(512) void k_aat(const float* __restrict__ A,
                                             float* __restrict__ C,
                                             _Float16* __restrict__ ATh) {
  __shared__ float As[64 * AST];
  int b = blockIdx.x >> 1;
  int p = blockIdx.x & 1;          // row-half: rows [64p, 64p+64)
  int tid = threadIdx.x;
  const float* Ab = A + (size_t)b * MM * NN;
  float* Cb = C + (size_t)b * MM * MM;
  _Float16* ATb = ATh + (size_t)b * NN * MM;
  int ig = tid >> 4;   // 0..31
  int jg = tid & 15;   // 0..15
  float acc[2][8];
#pragma unroll
  for (int aa = 0; aa < 2; ++aa)
#pragma unroll
    for (int cc = 0; cc < 8; ++cc) acc[aa][cc] = 0.0f;

  for (int t = 0; t < 16; ++t) {
    int k0 = t * 64;
#pragma unroll
    for (int s = 0; s < 4; ++s) {
      int c = tid + s * 512;        // 0..2047
      int m = c >> 4;               // 0..127
      int kk = (c & 15) << 2;       // 0..60
      float4 v = *(const float4*)&Ab[(size_t)m * NN + k0 + kk];
      As[(kk + 0) * AST + m] = v.x;
      As[(kk + 1) * AST + m] = v.y;
      As[(kk + 2) * AST + m] = v.z;
      As[(kk + 3) * AST + m] = v.w;
    }
    __syncthreads();
    // emit this block's half of the fp16 AT k-slice
#pragma unroll
    for (int s = 0; s < 4; ++s) {
      int idx = tid + s * 512;      // 0..2047
      int nl = 32 * p + (idx >> 6); // 32p..32p+31
      int mp = idx & 63;            // m-pair index
      half2v hv;
      hv[0] = (_Float16)As[nl * AST + 2 * mp];
      hv[1] = (_Float16)As[nl * AST + 2 * mp + 1];
      *(half2v*)&ATb[(size_t)(k0 + nl) * MM + 2 * mp] = hv;
    }
#pragma unroll 4
    for (int k = 0; k < 64; ++k) {
      float av[2], bv[8];
      av[0] = As[k * AST + 64 * p + ig];
      av[1] = As[k * AST + 64 * p + 32 + ig];
#pragma unroll
      for (int cc = 0; cc < 8; ++cc) bv[cc] = As[k * AST + jg + 16 * cc];
#pragma unroll
      for (int aa = 0; aa < 2; ++aa)
#pragma unroll
        for (int cc = 0; cc < 8; ++cc) acc[aa][cc] += av[aa] * bv[cc];
    }
    __syncthreads();
  }
#pragma unroll
  for (int aa = 0; aa < 2; ++aa)
#pragma unroll
    for (int cc = 0; cc < 8; ++cc)
      Cb[(size_t)(64 * p + ig + 32 * aa) * MM + jg + 16 * cc] = acc[aa][cc];
}

// ---------------------------------------------------------------------------
// In-place Gauss-Jordan inverse of SPD 128x128. 512 threads; stride-129 LDS;
// merged pivot-scale into the update -> 2 barriers/step.
#define IST 129
__global__ __launch_bounds__(512) void k_inv(float* __restrict__ G) {
  __shared__ float Msh[MM * IST];
  int b = blockIdx.x;
  int tid = threadIdx.x;
  float* Gb = G + (size_t)b * MM * MM;
#pragma unroll
  for (int s = 0; s < 8; ++s) {
    int idx = (tid + s * 512) * 4;
    float4 v = *(const float4*)&Gb[idx];
    int i = idx >> 7, j = idx & 127;
    Msh[i * IST + j + 0] = v.x;
    Msh[i * IST + j + 1] = v.y;
    Msh[i * IST + j + 2] = v.z;
    Msh[i * IST + j + 3] = v.w;
  }
  __syncthreads();
  int j = tid & 127;
  int i0 = (tid >> 7) * 32;   // this thread owns rows i0..i0+31, column j
  for (int k = 0; k < MM; ++k) {
    float p = 1.0f / Msh[k * IST + k];
    float mkj = Msh[k * IST + j];
    float fik[32];
#pragma unroll
    for (int ii = 0; ii < 32; ++ii) fik[ii] = Msh[(i0 + ii) * IST + k];
    __syncthreads();
    float pmkj = p * mkj;
#pragma unroll
    for (int ii = 0; ii < 32; ++ii) {
      int i = i0 + ii;
      float nij;
      if (i == k)
        nij = (j == k) ? p : pmkj;          // row k scaled; diag = 1/pivot
      else if (j == k)
        nij = -p * fik[ii];                 // col k
      else
        nij = Msh[i * IST + j] - fik[ii] * pmkj;
      Msh[i * IST + j] = nij;
    }
    __syncthreads();
  }
#pragma unroll
  for (int s = 0; s < 8; ++s) {
    int idx = (tid + s * 512) * 4;
    int i = idx >> 7, jj = idx & 127;
    float4 v;
    v.x = Msh[i * IST + jj + 0];
    v.y = Msh[i * IST + jj + 1];
    v.z = Msh[i * IST + jj + 2];
    v.w = Msh[i * IST + jj + 3];
    *(float4*)&Gb[idx] = v;
  }
}

// ---------------------------------------------------------------------------
// Persistent solver: one block per batch, 1024 threads (16 waves).
// Column placement per 16-lane group (16 cols total), sized to FIT IN 64
// VGPRs (the allocator hard-targets 8 waves/EU; >64 live regs = spill):
//   cols 64w+16..+31 : REGISTERS (af, 16 VGPRs, scalar-pinned)
//   cols 64w+32..+63 : LDS       (AL, 131 KB)
//   cols 64w+ 0..+15 : STREAMED from global each iter (65.5 KB/block ->
//                      2.1 MB/XCD, L2-resident; issued early, consumed last)
// z lives in LDS (broadcast reads); G fragment packed fp16 (8 VGPRs).
#define TRP 132
__global__ __attribute__((amdgpu_waves_per_eu(4, 4)))
__launch_bounds__(1024) void k_main(
    const _Float16* __restrict__ AT, const float* __restrict__ G,
    const float* __restrict__ bvec, const float* __restrict__ D1,
    const float* __restrict__ D2, float* __restrict__ out) {
  __shared__ __align__(16) _Float16 AL[512 * MM];   // 131 KB
  __shared__ float z_sh[NN];
  __shared__ float td_sh[NN];
  __shared__ float di_sh[NN];
  __shared__ float b_sh[MM];
  __shared__ __align__(16) _Float16 s_h[MM];
  __shared__ __align__(16) _Float16 u_h[MM];
  __shared__ __align__(16) float t_redW[16][TRP];

  int b = blockIdx.x;
  int tid = threadIdx.x;
  const _Float16* ATb = AT + (size_t)b * NN * MM;
  const float* Gb = G + (size_t)b * MM * MM;

  // ---- G fragment: 8 threads per row, 16 elems each, packed fp16 (8 VGPRs)
  int sub = tid & 7, r = tid >> 3;
  float ghf[8];
#pragma unroll
  for (int s = 0; s < 4; ++s) {
    float4 v = *(const float4*)&Gb[(size_t)r * MM + 16 * sub + 4 * s];
    half2v h0; h0[0] = (_Float16)v.x; h0[1] = (_Float16)v.y;
    half2v h1; h1[0] = (_Float16)v.z; h1[1] = (_Float16)v.w;
    ghf[2 * s + 0] = __builtin_bit_cast(float, h0);
    ghf[2 * s + 1] = __builtin_bit_cast(float, h1);
  }
#pragma unroll
  for (int s = 0; s < 8; ++s) asm volatile("" : "+v"(ghf[s]));
  {
    float d1 = D1[(size_t)b * NN + tid];
    float d2 = D2[(size_t)b * NN + tid];
    td_sh[tid] = ALPHA * fabsf(d1);
    di_sh[tid] = 1.0f / (1.0f + 2.0f * ALPHA * d2 * d2);
    z_sh[tid] = 0.0f;
  }
  if (tid < MM) {
    float bb = bvec[(size_t)b * MM + tid];
    b_sh[tid] = bb;
    s_h[tid] = (_Float16)(-bb);   // s_0 = A*y_0 - b = -b
  }

  int l16 = tid & 15;          // lane in 16-group
  int grp4 = (tid >> 4) & 3;   // group within wave
  int w = tid >> 6;            // wave 0..15
  int mbase = 8 * l16;

  // ---- LDS cols: AL col = 32*w + j  <->  n = 64*w + 32 + j  (j = 0..31)
#pragma unroll
  for (int i = 0; i < 8; ++i) {
    int c = tid + 1024 * i;          // 16B chunk id, 0..8191
    int col = c >> 4;                // 0..511 (16 chunks per col)
    int m8 = (c & 15) * 8;           // half-index within col
    int n = 32 * (col >> 5) + 32 + col;
    *(half8*)&AL[col * MM + m8] = *(const half8*)&ATb[(size_t)n * MM + m8];
  }

  // ---- register cols: n = 64*w + 16 + 4*j + grp4, j = 0..3 (16 VGPRs,
  // scalar-pinned so the allocator can neither remat nor "cheaply" drop them)
  float af0[4], af1[4], af2[4], af3[4];
#pragma unroll
  for (int j = 0; j < 4; ++j) {
    float4 v =
        *(const float4*)&ATb[(size_t)(64 * w + 16 + 4 * j + grp4) * MM + mbase];
    af0[j] = v.x; af1[j] = v.y; af2[j] = v.z; af3[j] = v.w;
  }
#pragma unroll
  for (int j = 0; j < 4; ++j) {
    asm volatile("" : "+v"(af0[j]));
    asm volatile("" : "+v"(af1[j]));
    asm volatile("" : "+v"(af2[j]));
    asm volatile("" : "+v"(af3[j]));
  }
  __syncthreads();

  for (int it = 0; it < ITERS; ++it) {
    bool last = (it == ITERS - 1);

    // ---- issue streamed-col loads early (cols 64w + 4j + grp4, j=0..3)
    float4 st[4];
#pragma unroll
    for (int j = 0; j < 4; ++j)
      st[j] = *(const float4*)&ATb[(size_t)(64 * w + 4 * j + grp4) * MM + mbase];

    // ---- u = G * s  (8 threads per row, packed fp16 dot)
    {
      int j0 = 16 * sub;
      half8 sA = *(const half8*)&s_h[j0];
      half8 sB = *(const half8*)&s_h[j0 + 8];
      float up = 0.0f;
      up = __builtin_amdgcn_fdot2(__builtin_bit_cast(half2v, ghf[0]),
                                  __builtin_shufflevector(sA, sA, 0, 1), up, false);
      up = __builtin_amdgcn_fdot2(__builtin_bit_cast(half2v, ghf[1]),
                                  __builtin_shufflevector(sA, sA, 2, 3), up, false);
      up = __builtin_amdgcn_fdot2(__builtin_bit_cast(half2v, ghf[2]),
                                  __builtin_shufflevector(sA, sA, 4, 5), up, false);
      up = __builtin_amdgcn_fdot2(__builtin_bit_cast(half2v, ghf[3]),
                                  __builtin_shufflevector(sA, sA, 6, 7), up, false);
      up = __builtin_amdgcn_fdot2(__builtin_bit_cast(half2v, ghf[4]),
                                  __builtin_shufflevector(sB, sB, 0, 1), up, false);
      up = __builtin_amdgcn_fdot2(__builtin_bit_cast(half2v, ghf[5]),
                                  __builtin_shufflevector(sB, sB, 2, 3), up, false);
      up = __builtin_amdgcn_fdot2(__builtin_bit_cast(half2v, ghf[6]),
                                  __builtin_shufflevector(sB, sB, 4, 5), up, false);
      up = __builtin_amdgcn_fdot2(__builtin_bit_cast(half2v, ghf[7]),
                                  __builtin_shufflevector(sB, sB, 6, 7), up, false);
      up += __shfl_xor(up, 1);
      up += __shfl_xor(up, 2);
      up += __shfl_xor(up, 4);
      if (sub == 0) u_h[r] = (_Float16)up;
    }
    __syncthreads();
    half8 uu = *(const half8*)&u_h[mbase];
    half2v u0 = __builtin_shufflevector(uu, uu, 0, 1);
    half2v u1 = __builtin_shufflevector(uu, uu, 2, 3);
    half2v u2 = __builtin_shufflevector(uu, uu, 4, 5);
    half2v u3 = __builtin_shufflevector(uu, uu, 6, 7);
    float t[8];
#pragma unroll
    for (int k = 0; k < 8; ++k) t[k] = 0.0f;

    auto colstep = [&](half2v a0, half2v a1, half2v a2, half2v a3, int n) {
      float cp = 0.0f;
      cp = __builtin_amdgcn_fdot2(a0, u0, cp, false);
      cp = __builtin_amdgcn_fdot2(a1, u1, cp, false);
      cp = __builtin_amdgcn_fdot2(a2, u2, cp, false);
      cp = __builtin_amdgcn_fdot2(a3, u3, cp, false);
      cp += __shfl_xor(cp, 1);
      cp += __shfl_xor(cp, 2);
      cp += __shfl_xor(cp, 4);
      cp += __shfl_xor(cp, 8);   // all 16 lanes hold corr[n]
      float zn = z_sh[n];        // broadcast
      float td = td_sh[n];
      float di = di_sh[n];
      float xm = zn - td, xp = zn + td;
      float xh = xm > 0.0f ? xm * di : (xp < 0.0f ? xp * di : 0.0f);
      if (!last) {
        float z1 = xh - cp;                     // z_{i+1}
        float xm1 = z1 - td, xp1 = z1 + td;
        float xh1 = xm1 > 0.0f ? xm1 * di : (xp1 < 0.0f ? xp1 * di : 0.0f);
        float y = 2.0f * xh1 - z1;              // y_{i+1}
        if (l16 == 0) z_sh[n] = z1;
        t[0] += (float)a0[0] * y; t[1] += (float)a0[1] * y;
        t[2] += (float)a1[0] * y; t[3] += (float)a1[1] * y;
        t[4] += (float)a2[0] * y; t[5] += (float)a2[1] * y;
        t[6] += (float)a3[0] * y; t[7] += (float)a3[1] * y;
      } else {
        float y = 2.0f * xh - zn;               // y_99 from z_99
        if (l16 == 0) z_sh[n] = y - cp;         // x_99 (output)
      }
    };

    // register cols first, then LDS cols, then streamed (loads have arrived)
#pragma unroll
    for (int j = 0; j < 4; ++j)
      colstep(__builtin_bit_cast(half2v, af0[j]),
              __builtin_bit_cast(half2v, af1[j]),
              __builtin_bit_cast(half2v, af2[j]),
              __builtin_bit_cast(half2v, af3[j]), 64 * w + 16 + 4 * j + grp4);
#pragma unroll
    for (int j = 0; j < 8; ++j) {
      half8 av = *(const half8*)&AL[(32 * w + 4 * j + grp4) * MM + mbase];
      colstep(__builtin_shufflevector(av, av, 0, 1),
              __builtin_shufflevector(av, av, 2, 3),
              __builtin_shufflevector(av, av, 4, 5),
              __builtin_shufflevector(av, av, 6, 7), 64 * w + 32 + 4 * j + grp4);
    }
#pragma unroll
    for (int j = 0; j < 4; ++j) {
      colstep(__builtin_bit_cast(half2v, st[j].x),
              __builtin_bit_cast(half2v, st[j].y),
              __builtin_bit_cast(half2v, st[j].z),
              __builtin_bit_cast(half2v, st[j].w), 64 * w + 4 * j + grp4);
    }

    if (!last) {
      // ---- in-wave cross-group reduce, then 16-wave LDS reduce
#pragma unroll
      for (int k = 0; k < 8; ++k) {
        t[k] += __shfl_xor(t[k], 16);
        t[k] += __shfl_xor(t[k], 32);
      }
      if (grp4 == 0) {
        float4 ta; ta.x = t[0]; ta.y = t[1]; ta.z = t[2]; ta.w = t[3];
        float4 tb; tb.x = t[4]; tb.y = t[5]; tb.z = t[6]; tb.w = t[7];
        *(float4*)&t_redW[w][mbase] = ta;
        *(float4*)&t_redW[w][mbase + 4] = tb;
      }
      __syncthreads();
      if (tid < MM) {
        float ssum = -b_sh[tid];
#pragma unroll
        for (int h = 0; h < 16; ++h) ssum += t_redW[h][tid];
        s_h[tid] = (_Float16)ssum;   // s = A*y - b for next pass's u
      }
      __syncthreads();
    }
  }

  __syncthreads();
  out[(size_t)b * NN + tid] = z_sh[tid];
}

// ---------------------------------------------------------------------------
extern "C" void kernel_launch(void* const* d_in, const int* in_sizes, int n_in,
                              void* d_out, int out_size, void* d_ws, size_t ws_size,
                              hipStream_t stream) {
  const float* A  = (const float*)d_in[0];  // (BS, M, N)
  const float* bv = (const float*)d_in[1];  // (BS, M)
  const float* D1 = (const float*)d_in[2];  // (BS, N)
  const float* D2 = (const float*)d_in[3];  // (BS, N)
  float* out = (float*)d_out;               // (BS, N)

  _Float16* ATh = (_Float16*)d_ws;                              // 67 MB
  float* G = (float*)((char*)d_ws + (size_t)BS * NN * MM * 2);  // 16.7 MB

  k_aat<<<BS * 2, 512, 0, stream>>>(A, G, ATh);
  k_inv<<<BS, 512, 0, stream>>>(G);
  k_main<<<BS, 1024, 0, stream>>>(ATh, G, bv, D1, D2, out);
}